// Round 8
// baseline (1764.232 us; speedup 1.0000x reference)
//
#include <hip/hip_runtime.h>

// LSTM net: linear1(20->50) -> 3x LSTMCell(50) (reference's buggy c-flow)
//   -> linear2(50->8).  B=512, T=1024.
//
// 256 blocks x 512 threads (8 waves = 2/SIMD), 1 block/CU, 2 batch/block.
// BASE = round-7 kernel (PASSED, 1727us): same lane map, same parities,
// same DPP/swzx4 combine, same L1/out windows.  ONE conceptual change:
//   NO INLINE ASM in the dot path.  r1-r7's op_sel pkfma asm forced every
//   weight operand into an ARCH VGPR at each use; with wv parked in the
//   AGPR half of the unified file the compiler emitted ~144 accvgpr_read
//   + tie-copies per lane per step (r7: ~625 VALU instrs/lane/step vs
//   ~200 useful).  Now LDS is batch-SEPARATED plain floats and the inner
//   loop is pure vector C (f32x4 acc += w * u) -> compiler-chosen
//   v_pk_fma_f32 / v_fmac with zero copy overhead.
// Octet k-chunks move 26->28 dims (vec4-aligned bases {0,28}); reads are
// zero-padded to 36 dims (pads audited never-written).  L1 windows {0,36}
// unchanged.  18 ds_read_b128/lane/step unchanged.
//
// Lane map: tid 0-399   octets (u=tid>>3): loc 0-3 L2 quad, 4-7 L3 quad;
//                        lane r=loc&3: side=r>>1 (in/rec), chunk=r&1
//           tid 400-499 L1 pairs (u=(tid-400)>>1), lane h: window 36h
//           tid 500-507 out-proj; tid 508-511 x-stage (4 lanes x 5 dims)
// Step s: L1 t=s, L2 t=s-1, L3 t=s-2 (P3 -> L2 same step via swzx4 =
//         reference's c2<-cell3 bug), out t=s-3.

#define T_SEQ 1024
#define IN_DIM 20
#define OUT_DIM 8

// LDS float offsets.  All buffers batch-separated: [parity][batch][len].
// Strides multiples of 32 floats -> 16B-slot invariant across parity/batch.
// vec4 streams per octet-wave instruction land on slots {5,4,0,7,2,1}.
#define CF   0      // C [2][2][96]: x 0-19, h1 20-69, pad 70-95
#define FH2  384    // h2 [2][2][64] (50 real + zero pad)
#define FH3  648    // h3 [2][2][64]  (384+256=640, +8 pad -> slot 2)
#define SMSZ 904

typedef float f32x2 __attribute__((ext_vector_type(2)));
typedef float f32x4 __attribute__((ext_vector_type(4)));

__device__ __forceinline__ float sigm(float x) {
    return __builtin_amdgcn_rcpf(1.0f + __expf(-x));
}
__device__ __forceinline__ float tanh_f(float x) {
    return fmaf(2.0f, sigm(2.0f * x), -1.0f);
}
__device__ __forceinline__ f32x2 sigm2(f32x2 v, float b) {
    f32x2 r; r.x = sigm(v.x + b); r.y = sigm(v.y + b); return r;
}
__device__ __forceinline__ float hsum4(f32x4 v) {
    const f32x2 t = v.lo + v.hi;
    return t.x + t.y;
}
template <int CTRL>   // quad_perm DPP: 0xB1 = lane^1, 0x4E = lane^2
__device__ __forceinline__ f32x2 dpp2(f32x2 v) {
    f32x2 r;
    r.x = __int_as_float(__builtin_amdgcn_mov_dpp(__float_as_int(v.x), CTRL, 0xF, 0xF, true));
    r.y = __int_as_float(__builtin_amdgcn_mov_dpp(__float_as_int(v.y), CTRL, 0xF, 0xF, true));
    return r;
}
__device__ __forceinline__ f32x2 swzx4(f32x2 v) {   // lane ^ 4 (bit-mode)
    f32x2 r;
    r.x = __int_as_float(__builtin_amdgcn_ds_swizzle(__float_as_int(v.x), 0x101F));
    r.y = __int_as_float(__builtin_amdgcn_ds_swizzle(__float_as_int(v.y), 0x101F));
    return r;
}

__global__ __launch_bounds__(512, 2)
__attribute__((amdgpu_waves_per_eu(2, 2)))
void lstm_net_kernel(
    const float* __restrict__ x,
    const float* __restrict__ W1,   const float* __restrict__ b1,
    const float* __restrict__ Wih1, const float* __restrict__ Whh1,
    const float* __restrict__ bih1, const float* __restrict__ bhh1,
    const float* __restrict__ Wih2, const float* __restrict__ Whh2,
    const float* __restrict__ bih2, const float* __restrict__ bhh2,
    const float* __restrict__ Wih3, const float* __restrict__ Whh3,
    const float* __restrict__ bih3, const float* __restrict__ bhh3,
    const float* __restrict__ W2,   const float* __restrict__ b2,
    float* __restrict__ out)
{
    __shared__ __align__(16) float smf[SMSZ];

    const int tid = threadIdx.x;
    const int b0  = blockIdx.x * 2;

    for (int i = tid; i < SMSZ; i += 512) smf[i] = 0.f;
    __syncthreads();

    f32x4 wv4[36];                       // 4 gates x 9 vec4 weight chunks
    #pragma unroll
    for (int i = 0; i < 36; i++) wv4[i] = (f32x4){0.f, 0.f, 0.f, 0.f};
    float bias4[4] = {0.f, 0.f, 0.f, 0.f};
    int   sel = 0, boff = 0, u = 0, loc = 0, ok = 0, sd = 0;
    bool  isOct = false, isL3 = false;
    f32x2 c1 = {0.f, 0.f};               // L1 cell (even L1 lanes)
    f32x2 xs[5];
    #pragma unroll
    for (int i = 0; i < 5; i++) xs[i] = (f32x2){0.f, 0.f};

    if (tid < 400) {                     // L2/L3 octets
        isOct = true;
        u = tid >> 3; loc = tid & 7; isL3 = (loc >= 4);
        const int r = loc & 3, side = r >> 1, chunk = r & 1;
        const int cb = 28 * chunk;       // own dims [cb, cb+28) ∩ [0,50)
        const float* src = isL3 ? (side ? Whh3 : Wih3) : (side ? Whh2 : Wih2);
        const float* bi  = isL3 ? bih3 : bih2;
        const float* bh  = isL3 ? bhh3 : bhh2;
        const int row4[4] = {u, 50 + u, 100 + u, 150 + u};   // i,f,g,o
        #pragma unroll
        for (int m = 0; m < 4; m++) {
            const bool dead = isL3 && (m == 1);              // f3 dead (c3==0)
            const int row = row4[m];
            #pragma unroll
            for (int i = 0; i < 9; i++) {
                f32x4 w = {0.f, 0.f, 0.f, 0.f};
                #pragma unroll
                for (int e = 0; e < 4; e++) {
                    const int k = 4 * i + e;      // rel to window base
                    const int d = cb + k;         // absolute dim
                    if (!dead && k < 28 && d < 50) w[e] = src[row * 50 + d];
                }
                wv4[m * 9 + i] = w;
            }
            bias4[m] = dead ? 0.f : bi[row] + bh[row];
        }
        if (!isL3) { sel = side ? 1 : 0; boff = side ? cb : 20 + cb; }
        else       { sel = side ? 2 : 1; boff = cb; }
    } else if (tid < 500) {              // L1 pairs, linear1 folded
        u = (tid - 400) >> 1;
        const int h = tid & 1;           // tid 400 -> abs lane 16: even
        sel = 0; boff = 36 * h;          // windows [0,36) and [36,70)
        const int row4[4] = {u, 50 + u, 100 + u, 150 + u};
        #pragma unroll
        for (int m = 0; m < 4; m++) {
            const int row = row4[m];
            float bs = bih1[row] + bhh1[row];
            for (int j = 0; j < 50; j++) bs = fmaf(Wih1[row * 50 + j], b1[j], bs);
            bias4[m] = bs;
            if (h == 0) {                // concat dims 0-35 = foldX(20)+h1(0-15)
                float a20[20];
                #pragma unroll
                for (int k = 0; k < 20; k++) a20[k] = 0.f;
                for (int j = 0; j < 50; j++) {
                    const float a = Wih1[row * 50 + j];
                    const float* w1r = W1 + j * 20;
                    #pragma unroll
                    for (int k = 0; k < 20; k++) a20[k] = fmaf(a, w1r[k], a20[k]);
                }
                #pragma unroll
                for (int i = 0; i < 9; i++) {
                    f32x4 w;
                    #pragma unroll
                    for (int e = 0; e < 4; e++) {
                        const int d = 4 * i + e;      // 0..35
                        w[e] = (d < 20) ? a20[d] : Whh1[row * 50 + (d - 20)];
                    }
                    wv4[m * 9 + i] = w;
                }
            } else {                     // concat dims 36-69 (h1 16-49), pad 70-71
                #pragma unroll
                for (int i = 0; i < 9; i++) {
                    f32x4 w = {0.f, 0.f, 0.f, 0.f};
                    #pragma unroll
                    for (int e = 0; e < 4; e++) {
                        const int d = 36 + 4 * i + e; // 36..71
                        if (d < 70) w[e] = Whh1[row * 50 + (d - 20)];
                    }
                    wv4[m * 9 + i] = w;
                }
            }
        }
    } else if (tid < 508) {              // out-proj: 13 vec4 (50 dims + 2 pad)
        ok = tid - 500;
        #pragma unroll
        for (int i = 0; i < 13; i++) {
            f32x4 w = {0.f, 0.f, 0.f, 0.f};
            #pragma unroll
            for (int e = 0; e < 4; e++) {
                const int d = 4 * i + e;
                if (d < 50) w[e] = W2[ok * 50 + d];
            }
            wv4[i] = w;
        }
        bias4[0] = b2[ok];
    } else {                             // x-stage: 4 lanes x dims {sd+4i}
        sd = tid - 508;
        for (int t = 0; t < 3; t++) {    // x(0)->C[0], x(1)->C[1], x(2)->regs
            #pragma unroll
            for (int i = 0; i < 5; i++) {
                const int dim = sd + 4 * i;
                f32x2 v;
                v.x = x[((size_t)b0 * T_SEQ + t) * IN_DIM + dim];
                v.y = x[((size_t)(b0 + 1) * T_SEQ + t) * IN_DIM + dim];
                if (t < 2) {
                    smf[CF + t * 192 + dim]      = v.x;
                    smf[CF + t * 192 + 96 + dim] = v.y;
                } else xs[i] = v;
            }
        }
    }
    __syncthreads();

    for (int s = 0; s < T_SEQ + 3; ++s) {
        const int p = s & 1, pm = p ^ 1;

        if (tid < 500) {                 // uniform gate path (octets + L1)
            const int bstr = (sel == 0) ? 96 : 64;   // batch stride
            const float* bp = smf
                + ((sel == 0) ? (CF + p * 192)
                 : (sel == 1) ? (FH2 + p * 128)
                              : (FH3 + pm * 128)) + boff;
            const f32x4* B0 = (const f32x4*)bp;
            const f32x4* B1 = (const f32x4*)(bp + bstr);
            f32x4 q00 = {0,0,0,0}, q01 = {0,0,0,0};
            f32x4 q10 = {0,0,0,0}, q11 = {0,0,0,0};
            f32x4 q20 = {0,0,0,0}, q21 = {0,0,0,0};
            f32x4 q30 = {0,0,0,0}, q31 = {0,0,0,0};
            #pragma unroll
            for (int i = 0; i < 9; i++) {
                const f32x4 u0 = B0[i], u1 = B1[i];
                q00 += wv4[i]      * u0;  q01 += wv4[i]      * u1;
                q10 += wv4[9 + i]  * u0;  q11 += wv4[9 + i]  * u1;
                q20 += wv4[18 + i] * u0;  q21 += wv4[18 + i] * u1;
                q30 += wv4[27 + i] * u0;  q31 += wv4[27 + i] * u1;
            }
            f32x2 A0 = {hsum4(q00), hsum4(q01)};
            f32x2 A1 = {hsum4(q10), hsum4(q11)};
            f32x2 A2 = {hsum4(q20), hsum4(q21)};
            f32x2 A3 = {hsum4(q30), hsum4(q31)};

            A0 += dpp2<0xB1>(A0); A1 += dpp2<0xB1>(A1);
            A2 += dpp2<0xB1>(A2); A3 += dpp2<0xB1>(A3);
            if (isOct) {                 // octets: full quad allreduce
                A0 += dpp2<0x4E>(A0); A1 += dpp2<0x4E>(A1);
                A2 += dpp2<0x4E>(A2); A3 += dpp2<0x4E>(A3);
            }
            const f32x2 ii = sigm2(A0, bias4[0]);
            const f32x2 ff = sigm2(A1, bias4[1]);
            f32x2 gg;
            gg.x = tanh_f(A2.x + bias4[2]);
            gg.y = tanh_f(A2.y + bias4[2]);
            const f32x2 oo = sigm2(A3, bias4[3]);
            f32x2 P = ii * gg;

            if (isOct) {
                const bool valid3 = (s >= 2) && (s < T_SEQ + 2);
                f32x2 ps = P;
                if (isL3 && !valid3) ps = (f32x2){0.f, 0.f};
                const f32x2 t4 = swzx4(ps);          // L2 lanes receive P3
                if (loc == 0) {                      // L2 combine, t2 = s-1
                    if (s >= 1 && s <= T_SEQ) {
                        f32x2 c2;
                        c2.x = fmaf(ff.x, t4.x, P.x);    // c2 = P2 + f2*P3
                        c2.y = fmaf(ff.y, t4.y, P.y);
                        smf[FH2 + pm * 128 + u]      = oo.x * tanh_f(c2.x);
                        smf[FH2 + pm * 128 + 64 + u] = oo.y * tanh_f(c2.y);
                    }
                } else if (loc == 4) {               // L3 combine, t3 = s-2
                    if (valid3) {                    // c3==0: cell = i3*g3
                        smf[FH3 + p * 128 + u]      = oo.x * tanh_f(P.x);
                        smf[FH3 + p * 128 + 64 + u] = oo.y * tanh_f(P.y);
                    }
                }
            } else {                                 // L1 combine, t1 = s
                if ((tid & 1) == 0 && s < T_SEQ) {
                    f32x2 cn;
                    cn.x = fmaf(ff.x, c1.x, P.x);    // cn = i*g + f*c1
                    cn.y = fmaf(ff.y, c1.y, P.y);
                    c1 = cn;
                    smf[CF + pm * 192 + 20 + u]      = oo.x * tanh_f(c1.x);
                    smf[CF + pm * 192 + 96 + 20 + u] = oo.y * tanh_f(c1.y);
                }
            }
        } else if (tid < 508) {          // out, t = s-3
            if (s >= 3) {
                const int t = s - 3;
                const f32x4* H0 = (const f32x4*)(smf + FH3 + pm * 128);
                const f32x4* H1 = (const f32x4*)(smf + FH3 + pm * 128 + 64);
                f32x4 a0 = {0,0,0,0}, a1 = {0,0,0,0};
                #pragma unroll
                for (int i = 0; i < 13; i++) {
                    a0 += wv4[i] * H0[i];
                    a1 += wv4[i] * H1[i];
                }
                out[((size_t)b0 * T_SEQ + t) * OUT_DIM + ok]       = hsum4(a0) + bias4[0];
                out[((size_t)(b0 + 1) * T_SEQ + t) * OUT_DIM + ok] = hsum4(a1) + bias4[0];
            }
        } else {                         // x-stage
            if (s >= 1 && s + 1 < T_SEQ) {           // commit x(s+1) -> C[pm]
                #pragma unroll
                for (int i = 0; i < 5; i++) {
                    const int dim = sd + 4 * i;
                    smf[CF + pm * 192 + dim]      = xs[i].x;
                    smf[CF + pm * 192 + 96 + dim] = xs[i].y;
                }
            }
            if (s + 2 < T_SEQ) {                     // load x(s+2) -> regs
                const int t = s + 2;
                #pragma unroll
                for (int i = 0; i < 5; i++) {
                    const int dim = sd + 4 * i;
                    xs[i].x = x[((size_t)b0 * T_SEQ + t) * IN_DIM + dim];
                    xs[i].y = x[((size_t)(b0 + 1) * T_SEQ + t) * IN_DIM + dim];
                }
            }
        }
        __syncthreads();
    }
}

extern "C" void kernel_launch(void* const* d_in, const int* in_sizes, int n_in,
                              void* d_out, int out_size, void* d_ws, size_t ws_size,
                              hipStream_t stream) {
    const float* x    = (const float*)d_in[0];
    const float* W1   = (const float*)d_in[1];
    const float* b1   = (const float*)d_in[2];
    const float* Wih1 = (const float*)d_in[3];
    const float* Whh1 = (const float*)d_in[4];
    const float* bih1 = (const float*)d_in[5];
    const float* bhh1 = (const float*)d_in[6];
    const float* Wih2 = (const float*)d_in[7];
    const float* Whh2 = (const float*)d_in[8];
    const float* bih2 = (const float*)d_in[9];
    const float* bhh2 = (const float*)d_in[10];
    const float* Wih3 = (const float*)d_in[11];
    const float* Whh3 = (const float*)d_in[12];
    const float* bih3 = (const float*)d_in[13];
    const float* bhh3 = (const float*)d_in[14];
    const float* W2   = (const float*)d_in[15];
    const float* b2   = (const float*)d_in[16];
    float* out = (float*)d_out;

    dim3 grid(256), block(512);
    lstm_net_kernel<<<grid, block, 0, stream>>>(
        x, W1, b1, Wih1, Whh1, bih1, bhh1, Wih2, Whh2, bih2, bhh2,
        Wih3, Whh3, bih3, bhh3, W2, b2, out);
}

// Round 10
// 1705.748 us; speedup vs baseline: 1.0343x; 1.0343x over previous
//
#include <hip/hip_runtime.h>

// LSTM net: linear1(20->50) -> 3x LSTMCell(50) (reference's buggy c-flow)
//   -> linear2(50->8).  B=512, T=1024.
//
// 256 blocks x 512 threads (8 waves = 2/SIMD), 1 block/CU, 2 batch/block.
// BASE = round-7 kernel (PASSED, 1727us), byte-identical semantics.
// ONE change: REMAT-PIN the weight array.
//   Theory (r5-r8 invariants): wv[] loads are const+restrict -> invariant
//   -> LLVM rematerializes-by-reload under pressure instead of keeping
//   them live: the 1027-step loop re-loads weights from L2/LLC each step
//   (invisible in FETCH_SIZE - HBM only; all blocks share one weight
//   copy).  Explains VGPR_Count~100 (working set only), 40% VALU idle
//   (L2 latency, 2 waves/SIMD), and the ~1700us plateau across 4
//   different dot codegens.  Pinning each wv[i] through asm("":"+v")
//   makes its def non-rematerializable -> RA must keep weights resident
//   (demand ~204 < 256 regs/wave at 2 waves/SIMD).
//
// Lane map: tid 0-399   octets (u=tid>>3): loc 0-3 L2 quad, 4-7 L3 quad;
//                        lane r=loc&3: side=r>>1 (in/rec), chunk=r&1
//           tid 400-499 L1 pairs (u=(tid-400)>>1), lane h: window 36h
//           tid 500-507 out-proj; tid 508-511 x-stage (4 lanes x 5 dims)
// Step s: L1 t=s, L2 t=s-1, L3 t=s-2 (P3 -> L2 same step via swzx4 =
//         reference's c2<-cell3 bug), out t=s-3.

#define T_SEQ 1024
#define IN_DIM 20
#define OUT_DIM 8

// LDS f32x2 ({batch0,batch1}) unit offsets.  16B-slot = (units/2) mod 8.
#define XC   0      // C [2][96]: 0-19 x, 20-69 h1, 70-95 pad0
#define CS   96     // C stride (96/2 % 8 == 0 -> slots parity-invariant)
#define XH2  192    // h2 [2][64]; chunk slots 0,5
#define XH3  322    // h3 [2][64]; chunk slots 1,6
#define SMSZ 450

typedef float f32x2 __attribute__((ext_vector_type(2)));
typedef float f32x4 __attribute__((ext_vector_type(4)));

// d += broadcast(w.lo)*u  /  d += broadcast(w.hi)*u   (VOP3P op_sel)
__device__ __forceinline__ void pkfma_lo(f32x2& d, f32x2 w, f32x2 u) {
    asm("v_pk_fma_f32 %0, %1, %2, %0 op_sel:[0,0,0] op_sel_hi:[0,1,1]"
        : "+v"(d) : "v"(w), "v"(u));
}
__device__ __forceinline__ void pkfma_hi(f32x2& d, f32x2 w, f32x2 u) {
    asm("v_pk_fma_f32 %0, %1, %2, %0 op_sel:[1,0,0] op_sel_hi:[1,1,1]"
        : "+v"(d) : "v"(w), "v"(u));
}
__device__ __forceinline__ float sigm(float x) {
    return __builtin_amdgcn_rcpf(1.0f + __expf(-x));
}
__device__ __forceinline__ float tanh_f(float x) {
    return fmaf(2.0f, sigm(2.0f * x), -1.0f);
}
__device__ __forceinline__ f32x2 sigm2(f32x2 v, float b) {
    f32x2 r; r.x = sigm(v.x + b); r.y = sigm(v.y + b); return r;
}
template <int CTRL>   // quad_perm DPP: 0xB1 = lane^1, 0x4E = lane^2
__device__ __forceinline__ f32x2 dpp2(f32x2 v) {
    f32x2 r;
    r.x = __int_as_float(__builtin_amdgcn_mov_dpp(__float_as_int(v.x), CTRL, 0xF, 0xF, true));
    r.y = __int_as_float(__builtin_amdgcn_mov_dpp(__float_as_int(v.y), CTRL, 0xF, 0xF, true));
    return r;
}
__device__ __forceinline__ f32x2 swzx4(f32x2 v) {   // lane ^ 4 (bit-mode)
    f32x2 r;
    r.x = __int_as_float(__builtin_amdgcn_ds_swizzle(__float_as_int(v.x), 0x101F));
    r.y = __int_as_float(__builtin_amdgcn_ds_swizzle(__float_as_int(v.y), 0x101F));
    return r;
}

__global__ __launch_bounds__(512, 2)
__attribute__((amdgpu_waves_per_eu(2, 2)))
void lstm_net_kernel(
    const float* __restrict__ x,
    const float* __restrict__ W1,   const float* __restrict__ b1,
    const float* __restrict__ Wih1, const float* __restrict__ Whh1,
    const float* __restrict__ bih1, const float* __restrict__ bhh1,
    const float* __restrict__ Wih2, const float* __restrict__ Whh2,
    const float* __restrict__ bih2, const float* __restrict__ bhh2,
    const float* __restrict__ Wih3, const float* __restrict__ Whh3,
    const float* __restrict__ bih3, const float* __restrict__ bhh3,
    const float* __restrict__ W2,   const float* __restrict__ b2,
    float* __restrict__ out)
{
    __shared__ __align__(16) f32x2 sm2[SMSZ];

    const int tid = threadIdx.x;
    const int b0  = blockIdx.x * 2;

    for (int i = tid; i < SMSZ; i += 512) sm2[i] = (f32x2){0.f, 0.f};
    __syncthreads();

    f32x2 wv[72];                        // 4 gates x 18 weight pairs
    #pragma unroll
    for (int i = 0; i < 72; i++) wv[i] = (f32x2){0.f, 0.f};
    float bias4[4] = {0.f, 0.f, 0.f, 0.f};
    int   sel = 0, boff = 0, u = 0, loc = 0, ok = 0, sd = 0;
    bool  isOct = false, isL3 = false;
    f32x2 c1 = {0.f, 0.f};               // L1 cell (even L1 lanes)
    f32x2 xs[5];
    #pragma unroll
    for (int i = 0; i < 5; i++) xs[i] = (f32x2){0.f, 0.f};

    if (tid < 400) {                     // L2/L3 octets
        isOct = true;
        u = tid >> 3; loc = tid & 7; isL3 = (loc >= 4);
        const int r = loc & 3, side = r >> 1, chunk = r & 1;
        const float* src = isL3 ? (side ? Whh3 : Wih3) : (side ? Whh2 : Wih2);
        const float* bi  = isL3 ? bih3 : bih2;
        const float* bh  = isL3 ? bhh3 : bhh2;
        const int row4[4] = {u, 50 + u, 100 + u, 150 + u};   // i,f,g,o
        #pragma unroll
        for (int m = 0; m < 4; m++) {
            const bool dead = isL3 && (m == 1);              // f3 dead (c3==0)
            const int row = row4[m];
            #pragma unroll
            for (int i = 0; i < 18; i++) {
                const int k0 = 2 * i, k1 = 2 * i + 1;
                const int d0 = 26 * chunk + k0, d1 = 26 * chunk + k1;
                const float w0 = (!dead && k0 < 26 && d0 < 50) ? src[row * 50 + d0] : 0.f;
                const float w1 = (!dead && k1 < 26 && d1 < 50) ? src[row * 50 + d1] : 0.f;
                wv[m * 18 + i] = (f32x2){w0, w1};
            }
            bias4[m] = dead ? 0.f : bi[row] + bh[row];
        }
        if (!isL3) { sel = side ? 1 : 0; boff = side ? 26 * chunk : 20 + 26 * chunk; }
        else       { sel = side ? 2 : 1; boff = 26 * chunk; }
    } else if (tid < 500) {              // L1 pairs, linear1 folded
        u = (tid - 400) >> 1;
        const int h = tid & 1;           // tid 400 -> abs lane 16: even
        sel = 0; boff = 36 * h;
        const int row4[4] = {u, 50 + u, 100 + u, 150 + u};
        #pragma unroll
        for (int m = 0; m < 4; m++) {
            const int row = row4[m];
            float bs = bih1[row] + bhh1[row];
            for (int j = 0; j < 50; j++) bs = fmaf(Wih1[row * 50 + j], b1[j], bs);
            bias4[m] = bs;
            if (h == 0) {                // concat dims 0-35 = foldX(20)+h1(0-15)
                float a20[20];
                #pragma unroll
                for (int k = 0; k < 20; k++) a20[k] = 0.f;
                for (int j = 0; j < 50; j++) {
                    const float a = Wih1[row * 50 + j];
                    const float* w1r = W1 + j * 20;
                    #pragma unroll
                    for (int k = 0; k < 20; k++) a20[k] = fmaf(a, w1r[k], a20[k]);
                }
                #pragma unroll
                for (int i = 0; i < 18; i++) {
                    const int k0 = 2 * i, k1 = 2 * i + 1;
                    const float w0 = (k0 < 20) ? a20[k0] : Whh1[row * 50 + (k0 - 20)];
                    const float w1 = (k1 < 20) ? a20[k1] : Whh1[row * 50 + (k1 - 20)];
                    wv[m * 18 + i] = (f32x2){w0, w1};
                }
            } else {                     // concat dims 36-69 = h1(16-49)+pad
                #pragma unroll
                for (int i = 0; i < 18; i++) {
                    const int k0 = 2 * i, k1 = 2 * i + 1;
                    const float w0 = (k0 < 34) ? Whh1[row * 50 + 16 + k0] : 0.f;
                    const float w1 = (k1 < 34) ? Whh1[row * 50 + 16 + k1] : 0.f;
                    wv[m * 18 + i] = (f32x2){w0, w1};
                }
            }
        }
    } else if (tid < 508) {              // out-proj
        ok = tid - 500;
        #pragma unroll
        for (int i = 0; i < 26; i++) {
            const int d0 = 2 * i, d1 = 2 * i + 1;
            const float w0 = (d0 < 50) ? W2[ok * 50 + d0] : 0.f;
            const float w1 = (d1 < 50) ? W2[ok * 50 + d1] : 0.f;
            wv[i] = (f32x2){w0, w1};
        }
        bias4[0] = b2[ok];
    } else {                             // x-stage: 4 lanes x dims {sd+4i}
        sd = tid - 508;
        for (int t = 0; t < 3; t++) {    // x(0)->C[0], x(1)->C[1], x(2)->regs
            #pragma unroll
            for (int i = 0; i < 5; i++) {
                const int dim = sd + 4 * i;
                f32x2 v;
                v.x = x[((size_t)b0 * T_SEQ + t) * IN_DIM + dim];
                v.y = x[((size_t)(b0 + 1) * T_SEQ + t) * IN_DIM + dim];
                if (t < 2) sm2[XC + t * CS + dim] = v;
                else       xs[i] = v;
            }
        }
    }

    // REMAT-PIN: def of each weight pair becomes this asm, not the
    // invariant global load -> the allocator cannot reload-per-use and
    // must keep all 72 pairs live across the step loop.
    #pragma unroll
    for (int i = 0; i < 72; i++) asm("" : "+v"(wv[i]));

    __syncthreads();

    for (int s = 0; s < T_SEQ + 3; ++s) {
        const int p = s & 1, pm = p ^ 1;

        if (tid < 500) {                 // uniform gate path (octets + L1)
            const int base = ((sel == 0) ? (XC + p * CS)
                            : (sel == 1) ? (XH2 + p * 64)
                                         : (XH3 + pm * 64)) + boff;
            const f32x4* B4 = (const f32x4*)(sm2 + base);
            f32x2 A0 = {0.f,0.f}, A1 = {0.f,0.f}, A2 = {0.f,0.f}, A3 = {0.f,0.f};
            #pragma unroll
            for (int i = 0; i < 18; i++) {
                const f32x4 uu = B4[i];
                const f32x2 ul = uu.lo, uh = uu.hi;
                pkfma_lo(A0, wv[i],      ul); pkfma_hi(A0, wv[i],      uh);
                pkfma_lo(A1, wv[18 + i], ul); pkfma_hi(A1, wv[18 + i], uh);
                pkfma_lo(A2, wv[36 + i], ul); pkfma_hi(A2, wv[36 + i], uh);
                pkfma_lo(A3, wv[54 + i], ul); pkfma_hi(A3, wv[54 + i], uh);
            }
            A0 += dpp2<0xB1>(A0); A1 += dpp2<0xB1>(A1);
            A2 += dpp2<0xB1>(A2); A3 += dpp2<0xB1>(A3);
            if (isOct) {                 // octets: full quad allreduce
                A0 += dpp2<0x4E>(A0); A1 += dpp2<0x4E>(A1);
                A2 += dpp2<0x4E>(A2); A3 += dpp2<0x4E>(A3);
            }
            const f32x2 ii = sigm2(A0, bias4[0]);
            const f32x2 ff = sigm2(A1, bias4[1]);
            f32x2 gg;
            gg.x = tanh_f(A2.x + bias4[2]);
            gg.y = tanh_f(A2.y + bias4[2]);
            const f32x2 oo = sigm2(A3, bias4[3]);
            f32x2 P = ii * gg;

            if (isOct) {
                const bool valid3 = (s >= 2) && (s < T_SEQ + 2);
                f32x2 ps = P;
                if (isL3 && !valid3) ps = (f32x2){0.f, 0.f};
                const f32x2 t4 = swzx4(ps);          // L2 lanes receive P3
                if (loc == 0) {                      // L2 combine, t2 = s-1
                    if (s >= 1 && s <= T_SEQ) {
                        f32x2 c2;
                        c2.x = fmaf(ff.x, t4.x, P.x);    // c2 = P2 + f2*P3
                        c2.y = fmaf(ff.y, t4.y, P.y);
                        f32x2 hh;
                        hh.x = oo.x * tanh_f(c2.x);
                        hh.y = oo.y * tanh_f(c2.y);
                        sm2[XH2 + pm * 64 + u] = hh; // slot t2&1 = pm
                    }
                } else if (loc == 4) {               // L3 combine, t3 = s-2
                    if (valid3) {                    // c3==0: cell = i3*g3
                        f32x2 hh;
                        hh.x = oo.x * tanh_f(P.x);
                        hh.y = oo.y * tanh_f(P.y);
                        sm2[XH3 + p * 64 + u] = hh;  // slot t3&1 = p
                    }
                }
            } else {                                 // L1 combine, t1 = s
                if ((tid & 1) == 0 && s < T_SEQ) {
                    f32x2 cn;
                    cn.x = fmaf(ff.x, c1.x, P.x);    // cn = i*g + f*c1
                    cn.y = fmaf(ff.y, c1.y, P.y);
                    c1 = cn;
                    f32x2 hh;
                    hh.x = oo.x * tanh_f(c1.x);
                    hh.y = oo.y * tanh_f(c1.y);
                    sm2[XC + pm * CS + 20 + u] = hh; // consumer-parity slot
                }
            }
        } else if (tid < 508) {          // out, t = s-3
            if (s >= 3) {
                const int t = s - 3;
                const f32x4* H4 = (const f32x4*)(sm2 + XH3 + pm * 64);
                f32x2 a0 = {0.f, 0.f}, a1 = {0.f, 0.f};
                #pragma unroll
                for (int i = 0; i < 26; i++) {
                    const f32x4 uu = H4[i];
                    pkfma_lo(a0, wv[i], uu.lo);
                    pkfma_hi(a1, wv[i], uu.hi);
                }
                const f32x2 acc = a0 + a1;
                out[((size_t)b0 * T_SEQ + t) * OUT_DIM + ok]       = acc.x + bias4[0];
                out[((size_t)(b0 + 1) * T_SEQ + t) * OUT_DIM + ok] = acc.y + bias4[0];
            }
        } else {                         // x-stage
            if (s >= 1 && s + 1 < T_SEQ) {           // commit x(s+1) -> C[pm]
                #pragma unroll
                for (int i = 0; i < 5; i++)
                    sm2[XC + pm * CS + sd + 4 * i] = xs[i];
            }
            if (s + 2 < T_SEQ) {                     // load x(s+2) -> regs
                const int t = s + 2;
                #pragma unroll
                for (int i = 0; i < 5; i++) {
                    const int dim = sd + 4 * i;
                    xs[i].x = x[((size_t)b0 * T_SEQ + t) * IN_DIM + dim];
                    xs[i].y = x[((size_t)(b0 + 1) * T_SEQ + t) * IN_DIM + dim];
                }
            }
        }
        __syncthreads();
    }
}

extern "C" void kernel_launch(void* const* d_in, const int* in_sizes, int n_in,
                              void* d_out, int out_size, void* d_ws, size_t ws_size,
                              hipStream_t stream) {
    const float* x    = (const float*)d_in[0];
    const float* W1   = (const float*)d_in[1];
    const float* b1   = (const float*)d_in[2];
    const float* Wih1 = (const float*)d_in[3];
    const float* Whh1 = (const float*)d_in[4];
    const float* bih1 = (const float*)d_in[5];
    const float* bhh1 = (const float*)d_in[6];
    const float* Wih2 = (const float*)d_in[7];
    const float* Whh2 = (const float*)d_in[8];
    const float* bih2 = (const float*)d_in[9];
    const float* bhh2 = (const float*)d_in[10];
    const float* Wih3 = (const float*)d_in[11];
    const float* Whh3 = (const float*)d_in[12];
    const float* bih3 = (const float*)d_in[13];
    const float* bhh3 = (const float*)d_in[14];
    const float* W2   = (const float*)d_in[15];
    const float* b2   = (const float*)d_in[16];
    float* out = (float*)d_out;

    dim3 grid(256), block(512);
    lstm_net_kernel<<<grid, block, 0, stream>>>(
        x, W1, b1, Wih1, Whh1, bih1, bhh1, Wih2, Whh2, bih2, bhh2,
        Wih3, Whh3, bih3, bhh3, W2, b2, out);
}